// Round 4
// baseline (361.261 us; speedup 1.0000x reference)
//
#include <hip/hip_runtime.h>
#include <math.h>

// Problem constants
#define MROWS   16384      // B*N
#define KCODES  8192
#define CDIM    256

// d_out layout (floats): [quantized 4194304][loss 1][indices 16384]
#define LOSS_OFF 4194304
#define IDXOFF   4194305

// ---- ws byte layout: pre-split f16 planes + reduction scratch (~27.3 MB) ----
#define NSPLIT  8
#define NPART   (NSPLIT * 2)                        // 16: 8 splits x 2 wave-columns
#define WS_ZH   0
#define WS_ZL   (WS_ZH + MROWS * CDIM * 2)
#define WS_EH   (WS_ZL + MROWS * CDIM * 2)
#define WS_EL   (WS_EH + KCODES * CDIM * 2)
#define WS_EN   (WS_EL + KCODES * CDIM * 2)         // float[8192]
#define WS_PV   (WS_EN + KCODES * 4)                // float[NPART*MROWS]
#define WS_PI   (WS_PV + NPART * MROWS * 4)         // int[NPART*MROWS]

// GEMM tiling
#define BM 128
#define BN 128
#define BK 32
#define CODES_PER_SPLIT (KCODES / NSPLIT)   // 1024
#define NTILES (CODES_PER_SPLIT / BN)       // 8

typedef float    v4f __attribute__((ext_vector_type(4)));
typedef _Float16 v8h __attribute__((ext_vector_type(8)));
typedef _Float16 v4h __attribute__((ext_vector_type(4)));

__device__ __forceinline__ void gload_lds16(const void* g, void* l) {
    __builtin_amdgcn_global_load_lds(
        (const __attribute__((address_space(1))) void*)g,
        (__attribute__((address_space(3))) void*)l, 16, 0, 0);
}

// ---------------------------------------------------------------------------
// Kernel 1: split fp32 -> f16 hi/lo planes for z and emb; ||e||^2; zero loss.
// One wave per row (64 lanes x float4 = 256 floats). 4 rows per block.
__global__ void split_enorm_kernel(const float* __restrict__ z,
                                   const float* __restrict__ emb,
                                   char* __restrict__ ws,
                                   float* __restrict__ loss_slot) {
    int tid = threadIdx.x;
    int w = tid >> 6, l = tid & 63;
    int row = blockIdx.x * 4 + w;
    const float4* src;
    _Float16 *hp, *lp;
    bool isE = (row >= MROWS);
    int u = row - MROWS;
    if (!isE) {
        src = (const float4*)(z + (size_t)row * CDIM);
        hp = (_Float16*)(ws + WS_ZH) + (size_t)row * CDIM;
        lp = (_Float16*)(ws + WS_ZL) + (size_t)row * CDIM;
    } else {
        src = (const float4*)(emb + (size_t)u * CDIM);
        hp = (_Float16*)(ws + WS_EH) + (size_t)u * CDIM;
        lp = (_Float16*)(ws + WS_EL) + (size_t)u * CDIM;
    }
    float4 v = src[l];
    v4h h, lo;
    h.x = (_Float16)v.x; lo.x = (_Float16)(v.x - (float)h.x);
    h.y = (_Float16)v.y; lo.y = (_Float16)(v.y - (float)h.y);
    h.z = (_Float16)v.z; lo.z = (_Float16)(v.z - (float)h.z);
    h.w = (_Float16)v.w; lo.w = (_Float16)(v.w - (float)h.w);
    *(v4h*)(hp + l * 4) = h;
    *(v4h*)(lp + l * 4) = lo;
    if (isE) {
        float s = v.x * v.x + v.y * v.y + v.z * v.z + v.w * v.w;
#pragma unroll
        for (int m = 32; m >= 1; m >>= 1) s += __shfl_xor(s, m, 64);
        if (l == 0) ((float*)(ws + WS_EN))[u] = s;
    }
    if (blockIdx.x == 0 && tid == 0) *loss_slot = 0.f;
}

// ---------------------------------------------------------------------------
// Kernel 2: split-f16 MFMA distance GEMM + fused argmin.
// BK=32 chunks, 32 KB LDS -> 4 blocks/CU (grid 1024 = one residency round).
// sp = blockIdx & 7 -> all blocks on one XCD share one E-plane slice
// (2.1 MB, fits the 4 MiB XCD L2). XOR swizzle on (row>>1)&3 over the 4
// 16B-chunks per row: fragment reads alias max 2-way (free).
__global__ __launch_bounds__(256, 4)
void vq_argmin_kernel(const char* __restrict__ ws_c, char* __restrict__ ws) {
    __shared__ __align__(16) _Float16 zsh[BM * BK];
    __shared__ __align__(16) _Float16 zsl[BM * BK];
    __shared__ __align__(16) _Float16 esh[BN * BK];
    __shared__ __align__(16) _Float16 esl[BN * BK];

    int tid  = threadIdx.x;
    int lane = tid & 63;
    int w    = tid >> 6;          // wave 0..3
    int tm   = lane & 15;         // MFMA m/n index
    int q    = lane >> 4;         // MFMA k-quad (= logical 16B chunk, BK=32)
    int wm   = w & 1, wn = w >> 1;
    int m0w  = wm * 64, n0w = wn * 64;

    int sp = blockIdx.x & 7;      // code split -> XCD
    int rb = blockIdx.x >> 3;     // row block 0..127
    int r0 = rb * BM;
    int cbase = sp * CODES_PER_SPLIT;

    // staging role: one wave per plane, 8 lds-DMA of 1 KB per chunk
    const char* gplane;
    char*       lplane;
    bool isE = (w >= 2);
    if      (w == 0) { gplane = ws_c + WS_ZH; lplane = (char*)zsh; }
    else if (w == 1) { gplane = ws_c + WS_ZL; lplane = (char*)zsl; }
    else if (w == 2) { gplane = ws_c + WS_EH; lplane = (char*)esh; }
    else             { gplane = ws_c + WS_EL; lplane = (char*)esl; }
    // lane -> (row-in-16-row-slab, phys chunk); source carries the swizzle:
    // content chunk = phys ^ ((row>>1)&3)
    int laneoff = (lane >> 2) * 512 + ((((lane) & 3) ^ ((lane >> 3) & 3)) << 4);

    // fragment read offsets (halves): row*32 + (q ^ ((tm>>1)&3))*8
    int p0 = ((q ^ ((tm >> 1) & 3)) << 3);
    int abase[4], bbase[4];
#pragma unroll
    for (int i = 0; i < 4; ++i) {
        abase[i] = (m0w + i * 16 + tm) * BK;
        bbase[i] = (n0w + i * 16 + tm) * BK;
    }

    const float* en_g = (const float*)(ws_c + WS_EN);
    const char* zsrc0 = gplane + (size_t)r0 * 512 + laneoff;   // z planes only

    float rmin[16];
    int   ridx[16];
#pragma unroll
    for (int s = 0; s < 16; ++s) { rmin[s] = 3e38f; ridx[s] = 0; }

    for (int tile = 0; tile < NTILES; ++tile) {
        int c0 = cbase + tile * BN;
        v4f acc[4][4];
#pragma unroll
        for (int i = 0; i < 4; ++i)
#pragma unroll
            for (int j = 0; j < 4; ++j) acc[i][j] = (v4f)0.f;

        const char* gsrc0 = isE ? (gplane + (size_t)c0 * 512 + laneoff) : zsrc0;

#pragma unroll 1
        for (int kt = 0; kt < CDIM / BK; ++kt) {   // 8 chunks
            __syncthreads();
            const char* src = gsrc0 + kt * 64;
#pragma unroll
            for (int i = 0; i < 8; ++i)
                gload_lds16(src + i * 8192, lplane + i * 1024);
            __syncthreads();

            v8h ah[4], al[4], bh[4], bl[4];
#pragma unroll
            for (int mi = 0; mi < 4; ++mi) {
                int o = abase[mi] + p0;
                ah[mi] = *(const v8h*)&zsh[o];
                al[mi] = *(const v8h*)&zsl[o];
            }
#pragma unroll
            for (int ni = 0; ni < 4; ++ni) {
                int o = bbase[ni] + p0;
                bh[ni] = *(const v8h*)&esh[o];
                bl[ni] = *(const v8h*)&esl[o];
            }
#pragma unroll
            for (int mi = 0; mi < 4; ++mi)
#pragma unroll
                for (int ni = 0; ni < 4; ++ni) {
                    acc[mi][ni] = __builtin_amdgcn_mfma_f32_16x16x32_f16(ah[mi], bh[ni], acc[mi][ni], 0, 0, 0);
                    acc[mi][ni] = __builtin_amdgcn_mfma_f32_16x16x32_f16(ah[mi], bl[ni], acc[mi][ni], 0, 0, 0);
                    acc[mi][ni] = __builtin_amdgcn_mfma_f32_16x16x32_f16(al[mi], bh[ni], acc[mi][ni], 0, 0, 0);
                }
        }

        // per-tile argmin update: score = ||e||^2 - 2*dot
#pragma unroll
        for (int ni = 0; ni < 4; ++ni) {
            int code = c0 + n0w + ni * 16 + tm;
            float en = en_g[code];
#pragma unroll
            for (int mi = 0; mi < 4; ++mi)
#pragma unroll
                for (int r = 0; r < 4; ++r) {
                    float s = fmaf(-2.f, acc[mi][ni][r], en);
                    int slot = mi * 4 + r;
                    if (s < rmin[slot]) { rmin[slot] = s; ridx[slot] = code; }
                }
        }
    }

    // reduce across the 16 column-lanes (tm) per row
#pragma unroll
    for (int slot = 0; slot < 16; ++slot) {
        float bv = rmin[slot];
        int   bi = ridx[slot];
#pragma unroll
        for (int m = 1; m <= 8; m <<= 1) {
            float v2 = __shfl_xor(bv, m, 64);
            int   i2 = __shfl_xor(bi, m, 64);
            if (v2 < bv || (v2 == bv && i2 < bi)) { bv = v2; bi = i2; }
        }
        if (tm == 0) {
            int grow = r0 + m0w + (slot >> 2) * 16 + q * 4 + (slot & 3);
            int part = sp * 2 + wn;
            ((float*)(ws + WS_PV))[part * MROWS + grow] = bv;
            ((int*)(ws + WS_PI))[part * MROWS + grow] = bi;
        }
    }
}

// ---------------------------------------------------------------------------
// Kernel 3: merge partials + gather + STE output + 1.25*MSE loss.
// Grid 256 x 256thr, 16 iterations; each wave iteration = one row (64 x
// float4). Lanes p=lane&15 load the 16 partials and shfl-reduce (all four
// 16-groups compute the same winner -> no broadcast).
__global__ void quant_loss_kernel(const float* __restrict__ z,
                                  const float* __restrict__ emb,
                                  const char* __restrict__ ws,
                                  float* __restrict__ out) {
    __shared__ float wsum[4];
    const float* pv = (const float*)(ws + WS_PV);
    const int*   pi = (const int*)(ws + WS_PI);
    int tid = threadIdx.x, lane = tid & 63;
    int p = lane & 15;
    float lsum = 0.f;
#pragma unroll 1
    for (int it = 0; it < 16; ++it) {
        int f = it * 65536 + blockIdx.x * 256 + tid;   // float4 index
        int row = f >> 6, c4 = f & 63;
        float bv = pv[p * MROWS + row];
        int   bi = pi[p * MROWS + row];
#pragma unroll
        for (int m = 1; m <= 8; m <<= 1) {
            float v2 = __shfl_xor(bv, m, 64);
            int   i2 = __shfl_xor(bi, m, 64);
            if (v2 < bv || (v2 == bv && i2 < bi)) { bv = v2; bi = i2; }
        }
        if (c4 == 0) out[IDXOFF + row] = (float)bi;
        float4 qv = ((const float4*)(emb + (size_t)bi * CDIM))[c4];
        float4 zv = ((const float4*)z)[f];
        float dx = qv.x - zv.x, dy = qv.y - zv.y;
        float dz = qv.z - zv.z, dw = qv.w - zv.w;
        float4 o;   // match reference STE rounding: z + (q - z)
        o.x = zv.x + dx; o.y = zv.y + dy; o.z = zv.z + dz; o.w = zv.w + dw;
        ((float4*)out)[f] = o;
        lsum += dx * dx + dy * dy + dz * dz + dw * dw;
    }
#pragma unroll
    for (int m = 32; m >= 1; m >>= 1) lsum += __shfl_xor(lsum, m, 64);
    int wv = tid >> 6;
    if (lane == 0) wsum[wv] = lsum;
    __syncthreads();
    if (tid == 0) {
        float t = wsum[0] + wsum[1] + wsum[2] + wsum[3];
        atomicAdd(out + LOSS_OFF, t * (1.25f / 4194304.f));
    }
}

// ---------------------------------------------------------------------------
extern "C" void kernel_launch(void* const* d_in, const int* in_sizes, int n_in,
                              void* d_out, int out_size, void* d_ws, size_t ws_size,
                              hipStream_t stream) {
    const float* z   = (const float*)d_in[0];
    const float* emb = (const float*)d_in[1];
    float* out = (float*)d_out;
    char*  ws  = (char*)d_ws;   // ~27.3 MB used

    hipLaunchKernelGGL(split_enorm_kernel, dim3((MROWS + KCODES) / 4), dim3(256),
                       0, stream, z, emb, ws, out + LOSS_OFF);
    hipLaunchKernelGGL(vq_argmin_kernel, dim3((MROWS / BM) * NSPLIT), dim3(256),
                       0, stream, ws, ws);
    hipLaunchKernelGGL(quant_loss_kernel, dim3(256), dim3(256),
                       0, stream, z, emb, ws, out);
}

// Round 5
// 320.081 us; speedup vs baseline: 1.1287x; 1.1287x over previous
//
#include <hip/hip_runtime.h>
#include <math.h>

// Problem constants
#define MROWS   16384      // B*N
#define KCODES  8192
#define CDIM    256

// d_out layout (floats): [quantized 4194304][loss 1][indices 16384]
#define LOSS_OFF 4194304
#define IDXOFF   4194305

// ---- ws byte layout: pre-split f16 planes + reduction scratch (~27.3 MB) ----
#define NSPLIT  8
#define NPART   (NSPLIT * 2)                        // 16: 8 splits x 2 wave-columns
#define WS_ZH   0
#define WS_ZL   (WS_ZH + MROWS * CDIM * 2)
#define WS_EH   (WS_ZL + MROWS * CDIM * 2)
#define WS_EL   (WS_EH + KCODES * CDIM * 2)
#define WS_EN   (WS_EL + KCODES * CDIM * 2)         // float[8192]
#define WS_PV   (WS_EN + KCODES * 4)                // float[NPART*MROWS]
#define WS_PI   (WS_PV + NPART * MROWS * 4)         // int[NPART*MROWS]

// GEMM tiling
#define BM 128
#define BN 128
#define BK 32
#define CODES_PER_SPLIT (KCODES / NSPLIT)   // 1024
#define NTILES (CODES_PER_SPLIT / BN)       // 8

typedef float    v4f __attribute__((ext_vector_type(4)));
typedef _Float16 v8h __attribute__((ext_vector_type(8)));
typedef _Float16 v4h __attribute__((ext_vector_type(4)));

__device__ __forceinline__ void gload_lds16(const void* g, void* l) {
    __builtin_amdgcn_global_load_lds(
        (const __attribute__((address_space(1))) void*)g,
        (__attribute__((address_space(3))) void*)l, 16, 0, 0);
}

// ---------------------------------------------------------------------------
// Kernel 1: split fp32 -> f16 hi/lo planes for z and emb; ||e||^2; zero loss.
__global__ void split_enorm_kernel(const float* __restrict__ z,
                                   const float* __restrict__ emb,
                                   char* __restrict__ ws,
                                   float* __restrict__ loss_slot) {
    int tid = threadIdx.x;
    int w = tid >> 6, l = tid & 63;
    int row = blockIdx.x * 4 + w;
    const float4* src;
    _Float16 *hp, *lp;
    bool isE = (row >= MROWS);
    int u = row - MROWS;
    if (!isE) {
        src = (const float4*)(z + (size_t)row * CDIM);
        hp = (_Float16*)(ws + WS_ZH) + (size_t)row * CDIM;
        lp = (_Float16*)(ws + WS_ZL) + (size_t)row * CDIM;
    } else {
        src = (const float4*)(emb + (size_t)u * CDIM);
        hp = (_Float16*)(ws + WS_EH) + (size_t)u * CDIM;
        lp = (_Float16*)(ws + WS_EL) + (size_t)u * CDIM;
    }
    float4 v = src[l];
    v4h h, lo;
    h.x = (_Float16)v.x; lo.x = (_Float16)(v.x - (float)h.x);
    h.y = (_Float16)v.y; lo.y = (_Float16)(v.y - (float)h.y);
    h.z = (_Float16)v.z; lo.z = (_Float16)(v.z - (float)h.z);
    h.w = (_Float16)v.w; lo.w = (_Float16)(v.w - (float)h.w);
    *(v4h*)(hp + l * 4) = h;
    *(v4h*)(lp + l * 4) = lo;
    if (isE) {
        float s = v.x * v.x + v.y * v.y + v.z * v.z + v.w * v.w;
#pragma unroll
        for (int m = 32; m >= 1; m >>= 1) s += __shfl_xor(s, m, 64);
        if (l == 0) ((float*)(ws + WS_EN))[u] = s;
    }
    if (blockIdx.x == 0 && tid == 0) *loss_slot = 0.f;
}

// ---------------------------------------------------------------------------
// Kernel 2: split-f16 MFMA distance GEMM + fused argmin.
// BK=32, 32 KB LDS. __launch_bounds__(256,3): VGPR cap ~170 so the
// 64-reg accumulator + 32-reg argmin state + fragments fit WITHOUT spills
// (round 4's (256,4) capped at 128 -> 199 MB of scratch spill traffic).
// 3 blocks/CU resident hide the per-kt barrier drains.
// sp = high bits: temporally adjacent blocks share one 2 MB E-slice (L2).
__global__ __launch_bounds__(256, 3)
void vq_argmin_kernel(const char* __restrict__ ws_c, char* __restrict__ ws) {
    __shared__ __align__(16) _Float16 zsh[BM * BK];
    __shared__ __align__(16) _Float16 zsl[BM * BK];
    __shared__ __align__(16) _Float16 esh[BN * BK];
    __shared__ __align__(16) _Float16 esl[BN * BK];

    int tid  = threadIdx.x;
    int lane = tid & 63;
    int w    = tid >> 6;          // wave 0..3
    int tm   = lane & 15;         // MFMA m/n index
    int q    = lane >> 4;         // MFMA k-quad (= logical 16B chunk, BK=32)
    int wm   = w & 1, wn = w >> 1;
    int m0w  = wm * 64, n0w = wn * 64;

    int rb = blockIdx.x & 127;    // row block (consecutive blocks: same split)
    int sp = blockIdx.x >> 7;     // code split
    int r0 = rb * BM;
    int cbase = sp * CODES_PER_SPLIT;

    // staging role: one wave per plane, 8 lds-DMA of 1 KB per chunk
    const char* gplane;
    char*       lplane;
    bool isE = (w >= 2);
    if      (w == 0) { gplane = ws_c + WS_ZH; lplane = (char*)zsh; }
    else if (w == 1) { gplane = ws_c + WS_ZL; lplane = (char*)zsl; }
    else if (w == 2) { gplane = ws_c + WS_EH; lplane = (char*)esh; }
    else             { gplane = ws_c + WS_EL; lplane = (char*)esl; }
    // lane -> (row-in-16-row-slab, phys chunk); source carries the swizzle:
    // content chunk = phys ^ ((row>>1)&3)
    int laneoff = (lane >> 2) * 512 + ((((lane) & 3) ^ ((lane >> 3) & 3)) << 4);

    // fragment read offsets (halves): row*32 + (q ^ ((tm>>1)&3))*8
    int p0 = ((q ^ ((tm >> 1) & 3)) << 3);
    int abase[4], bbase[4];
#pragma unroll
    for (int i = 0; i < 4; ++i) {
        abase[i] = (m0w + i * 16 + tm) * BK;
        bbase[i] = (n0w + i * 16 + tm) * BK;
    }

    const float* en_g = (const float*)(ws_c + WS_EN);
    const char* zsrc0 = gplane + (size_t)r0 * 512 + laneoff;   // z planes only

    float rmin[16];
    int   ridx[16];
#pragma unroll
    for (int s = 0; s < 16; ++s) { rmin[s] = 3e38f; ridx[s] = 0; }

    for (int tile = 0; tile < NTILES; ++tile) {
        int c0 = cbase + tile * BN;
        v4f acc[4][4];
#pragma unroll
        for (int i = 0; i < 4; ++i)
#pragma unroll
            for (int j = 0; j < 4; ++j) acc[i][j] = (v4f)0.f;

        const char* gsrc0 = isE ? (gplane + (size_t)c0 * 512 + laneoff) : zsrc0;

#pragma unroll 1
        for (int kt = 0; kt < CDIM / BK; ++kt) {   // 8 chunks
            __syncthreads();
            const char* src = gsrc0 + kt * 64;
#pragma unroll
            for (int i = 0; i < 8; ++i)
                gload_lds16(src + i * 8192, lplane + i * 1024);
            __syncthreads();

            v8h ah[4], al[4], bh[4], bl[4];
#pragma unroll
            for (int mi = 0; mi < 4; ++mi) {
                int o = abase[mi] + p0;
                ah[mi] = *(const v8h*)&zsh[o];
                al[mi] = *(const v8h*)&zsl[o];
            }
#pragma unroll
            for (int ni = 0; ni < 4; ++ni) {
                int o = bbase[ni] + p0;
                bh[ni] = *(const v8h*)&esh[o];
                bl[ni] = *(const v8h*)&esl[o];
            }
#pragma unroll
            for (int mi = 0; mi < 4; ++mi)
#pragma unroll
                for (int ni = 0; ni < 4; ++ni) {
                    acc[mi][ni] = __builtin_amdgcn_mfma_f32_16x16x32_f16(ah[mi], bh[ni], acc[mi][ni], 0, 0, 0);
                    acc[mi][ni] = __builtin_amdgcn_mfma_f32_16x16x32_f16(ah[mi], bl[ni], acc[mi][ni], 0, 0, 0);
                    acc[mi][ni] = __builtin_amdgcn_mfma_f32_16x16x32_f16(al[mi], bh[ni], acc[mi][ni], 0, 0, 0);
                }
        }

        // per-tile argmin update: score = ||e||^2 - 2*dot
#pragma unroll
        for (int ni = 0; ni < 4; ++ni) {
            int code = c0 + n0w + ni * 16 + tm;
            float en = en_g[code];
#pragma unroll
            for (int mi = 0; mi < 4; ++mi)
#pragma unroll
                for (int r = 0; r < 4; ++r) {
                    float s = fmaf(-2.f, acc[mi][ni][r], en);
                    int slot = mi * 4 + r;
                    if (s < rmin[slot]) { rmin[slot] = s; ridx[slot] = code; }
                }
        }
    }

    // reduce across the 16 column-lanes (tm) per row
#pragma unroll
    for (int slot = 0; slot < 16; ++slot) {
        float bv = rmin[slot];
        int   bi = ridx[slot];
#pragma unroll
        for (int m = 1; m <= 8; m <<= 1) {
            float v2 = __shfl_xor(bv, m, 64);
            int   i2 = __shfl_xor(bi, m, 64);
            if (v2 < bv || (v2 == bv && i2 < bi)) { bv = v2; bi = i2; }
        }
        if (tm == 0) {
            int grow = r0 + m0w + (slot >> 2) * 16 + q * 4 + (slot & 3);
            int part = sp * 2 + wn;
            ((float*)(ws + WS_PV))[part * MROWS + grow] = bv;
            ((int*)(ws + WS_PI))[part * MROWS + grow] = bi;
        }
    }
}

// ---------------------------------------------------------------------------
// Kernel 3: merge partials + gather + STE output + 1.25*MSE loss.
__global__ void quant_loss_kernel(const float* __restrict__ z,
                                  const float* __restrict__ emb,
                                  const char* __restrict__ ws,
                                  float* __restrict__ out) {
    __shared__ float wsum[4];
    const float* pv = (const float*)(ws + WS_PV);
    const int*   pi = (const int*)(ws + WS_PI);
    int tid = threadIdx.x, lane = tid & 63;
    int p = lane & 15;
    float lsum = 0.f;
#pragma unroll 1
    for (int it = 0; it < 16; ++it) {
        int f = it * 65536 + blockIdx.x * 256 + tid;   // float4 index
        int row = f >> 6, c4 = f & 63;
        float bv = pv[p * MROWS + row];
        int   bi = pi[p * MROWS + row];
#pragma unroll
        for (int m = 1; m <= 8; m <<= 1) {
            float v2 = __shfl_xor(bv, m, 64);
            int   i2 = __shfl_xor(bi, m, 64);
            if (v2 < bv || (v2 == bv && i2 < bi)) { bv = v2; bi = i2; }
        }
        if (c4 == 0) out[IDXOFF + row] = (float)bi;
        float4 qv = ((const float4*)(emb + (size_t)bi * CDIM))[c4];
        float4 zv = ((const float4*)z)[f];
        float dx = qv.x - zv.x, dy = qv.y - zv.y;
        float dz = qv.z - zv.z, dw = qv.w - zv.w;
        float4 o;   // match reference STE rounding: z + (q - z)
        o.x = zv.x + dx; o.y = zv.y + dy; o.z = zv.z + dz; o.w = zv.w + dw;
        ((float4*)out)[f] = o;
        lsum += dx * dx + dy * dy + dz * dz + dw * dw;
    }
#pragma unroll
    for (int m = 32; m >= 1; m >>= 1) lsum += __shfl_xor(lsum, m, 64);
    int wv = tid >> 6;
    if (lane == 0) wsum[wv] = lsum;
    __syncthreads();
    if (tid == 0) {
        float t = wsum[0] + wsum[1] + wsum[2] + wsum[3];
        atomicAdd(out + LOSS_OFF, t * (1.25f / 4194304.f));
    }
}

// ---------------------------------------------------------------------------
extern "C" void kernel_launch(void* const* d_in, const int* in_sizes, int n_in,
                              void* d_out, int out_size, void* d_ws, size_t ws_size,
                              hipStream_t stream) {
    const float* z   = (const float*)d_in[0];
    const float* emb = (const float*)d_in[1];
    float* out = (float*)d_out;
    char*  ws  = (char*)d_ws;   // ~27.3 MB used

    hipLaunchKernelGGL(split_enorm_kernel, dim3((MROWS + KCODES) / 4), dim3(256),
                       0, stream, z, emb, ws, out + LOSS_OFF);
    hipLaunchKernelGGL(vq_argmin_kernel, dim3((MROWS / BM) * NSPLIT), dim3(256),
                       0, stream, ws, ws);
    hipLaunchKernelGGL(quant_loss_kernel, dim3(256), dim3(256),
                       0, stream, z, emb, ws, out);
}

// Round 6
// 255.029 us; speedup vs baseline: 1.4166x; 1.2551x over previous
//
#include <hip/hip_runtime.h>
#include <math.h>

// Problem constants
#define MROWS   16384      // B*N
#define KCODES  8192
#define CDIM    256

// d_out layout (floats): [quantized 4194304][loss 1][indices 16384]
#define LOSS_OFF 4194304
#define IDXOFF   4194305

// ---- ws byte layout: pre-split f16 planes + reduction scratch (~25.7 MB) ----
#define NSPLIT  4
#define NPART   NSPLIT                              // 4 code splits, 1 partial each
#define WS_ZH   0
#define WS_ZL   (WS_ZH + MROWS * CDIM * 2)
#define WS_EH   (WS_ZL + MROWS * CDIM * 2)
#define WS_EL   (WS_EH + KCODES * CDIM * 2)
#define WS_EN   (WS_EL + KCODES * CDIM * 2)         // float[8192]
#define WS_PV   (WS_EN + KCODES * 4)                // float[NPART*MROWS]
#define WS_PI   (WS_PV + NPART * MROWS * 4)         // int[NPART*MROWS]

// Tiling: block = 128 rows x 2048 codes (one split); per barrier-segment a
// 32-code x full-K (256) E tile is staged (32 KB LDS); each wave owns 32 rows
// with its z A-fragments (full K, hi+lo) pinned in registers (128 VGPRs).
#define BM 128
#define BNT 32                              // codes per staged tile
#define CODES_PER_SPLIT (KCODES / NSPLIT)   // 2048
#define NTILES (CODES_PER_SPLIT / BNT)      // 64

typedef float    v4f __attribute__((ext_vector_type(4)));
typedef _Float16 v8h __attribute__((ext_vector_type(8)));
typedef _Float16 v4h __attribute__((ext_vector_type(4)));

__device__ __forceinline__ void gload_lds16(const void* g, void* l) {
    __builtin_amdgcn_global_load_lds(
        (const __attribute__((address_space(1))) void*)g,
        (__attribute__((address_space(3))) void*)l, 16, 0, 0);
}

// ---------------------------------------------------------------------------
// Kernel 1: split fp32 -> f16 hi/lo planes for z and emb; ||e||^2; zero loss.
__global__ void split_enorm_kernel(const float* __restrict__ z,
                                   const float* __restrict__ emb,
                                   char* __restrict__ ws,
                                   float* __restrict__ loss_slot) {
    int tid = threadIdx.x;
    int w = tid >> 6, l = tid & 63;
    int row = blockIdx.x * 4 + w;
    const float4* src;
    _Float16 *hp, *lp;
    bool isE = (row >= MROWS);
    int u = row - MROWS;
    if (!isE) {
        src = (const float4*)(z + (size_t)row * CDIM);
        hp = (_Float16*)(ws + WS_ZH) + (size_t)row * CDIM;
        lp = (_Float16*)(ws + WS_ZL) + (size_t)row * CDIM;
    } else {
        src = (const float4*)(emb + (size_t)u * CDIM);
        hp = (_Float16*)(ws + WS_EH) + (size_t)u * CDIM;
        lp = (_Float16*)(ws + WS_EL) + (size_t)u * CDIM;
    }
    float4 v = src[l];
    v4h h, lo;
    h.x = (_Float16)v.x; lo.x = (_Float16)(v.x - (float)h.x);
    h.y = (_Float16)v.y; lo.y = (_Float16)(v.y - (float)h.y);
    h.z = (_Float16)v.z; lo.z = (_Float16)(v.z - (float)h.z);
    h.w = (_Float16)v.w; lo.w = (_Float16)(v.w - (float)h.w);
    *(v4h*)(hp + l * 4) = h;
    *(v4h*)(lp + l * 4) = lo;
    if (isE) {
        float s = v.x * v.x + v.y * v.y + v.z * v.z + v.w * v.w;
#pragma unroll
        for (int m = 32; m >= 1; m >>= 1) s += __shfl_xor(s, m, 64);
        if (l == 0) ((float*)(ws + WS_EN))[u] = s;
    }
    if (blockIdx.x == 0 && tid == 0) *loss_slot = 0.f;
}

// ---------------------------------------------------------------------------
// Kernel 2: split-f16 MFMA distance GEMM + fused argmin, z-in-registers.
// Grid 512 = 128 row-blocks x 4 splits; sp = blockIdx&3 so round-robin
// dispatch gives each XCD one 2 MB E-slice (L2-resident).
// LDS: one 32-code x 256-half E tile per plane (32 KB total). Swizzle:
// phys 16B-chunk = logical ^ (code&7) (baked into DMA *source* address);
// b128 fragment reads then hit 8 distinct bank-groups per 8-lane phase.
__global__ __launch_bounds__(256, 2)
void vq_argmin_kernel(const char* __restrict__ ws_c, char* __restrict__ ws) {
    __shared__ __align__(16) _Float16 esh[BNT * CDIM];   // 16 KB
    __shared__ __align__(16) _Float16 esl[BNT * CDIM];   // 16 KB

    int tid  = threadIdx.x;
    int lane = tid & 63;
    int w    = tid >> 6;          // wave 0..3 (owns rows w*32 .. w*32+31)
    int tm   = lane & 15;         // MFMA m/n index
    int q    = lane >> 4;         // MFMA k-quad

    int sp = blockIdx.x & 3;      // code split -> XCD-resident slice
    int rb = blockIdx.x >> 2;     // row block 0..127
    int r0 = rb * BM;
    int cbase = sp * CODES_PER_SPLIT;

    // ---- prologue: pin z A-fragments (full K, hi+lo) in registers ----
    const _Float16* zh_g = (const _Float16*)(ws_c + WS_ZH);
    const _Float16* zl_g = (const _Float16*)(ws_c + WS_ZL);
    v8h zfh[2][8], zfl[2][8];
    {
        int rowb = r0 + w * 32 + tm;
#pragma unroll
        for (int mi = 0; mi < 2; ++mi)
#pragma unroll
            for (int kc = 0; kc < 8; ++kc) {
                size_t off = (size_t)(rowb + mi * 16) * CDIM + kc * 32 + q * 8;
                zfh[mi][kc] = *(const v8h*)(zh_g + off);
                zfl[mi][kc] = *(const v8h*)(zl_g + off);
            }
    }

    // ---- staging assignment: wave -> (plane, 16 codes), 8 x 1 KB DMAs ----
    int p  = w >> 1;              // 0: hi plane, 1: lo plane
    int cw = (w & 1) * 16;        // code sub-range within the 32-code tile
    const char* egp = ws_c + (p ? WS_EL : WS_EH);
    char* ldst = (char*)(p ? esl : esh) + cw * 512;
    int l5 = lane >> 5, c31 = lane & 31;
    int rel[4];
#pragma unroll
    for (int i = 0; i < 4; ++i) {
        int c = cw + 2 * i + l5;                     // code within tile
        rel[i] = c * 512 + ((c31 ^ (c & 7)) << 4);   // swizzled source offset
    }

    // ---- fragment-read offsets (halves): code*256 + swizzled chunk ----
    int hb  = (tm >> 2) & 1;
    int qx  = q ^ (tm & 3);
    int eb0 = tm * 256 + qx * 8;          // ni = 0 (codes c0+tm)
    int eb1 = (16 + tm) * 256 + qx * 8;   // ni = 1 (codes c0+16+tm)

    const float* en_g = (const float*)(ws_c + WS_EN);

    float rmin[8];
    int   ridx[8];
#pragma unroll
    for (int s = 0; s < 8; ++s) { rmin[s] = 3e38f; ridx[s] = 0; }

    const char* tb = egp + (size_t)cbase * 512;

#pragma unroll 1
    for (int tile = 0; tile < NTILES; ++tile) {
        __syncthreads();                   // previous tile's reads done
#pragma unroll
        for (int i = 0; i < 8; ++i)
            gload_lds16(tb + rel[i & 3] + (i >> 2) * 4096, ldst + i * 1024);
        int c0 = cbase + tile * BNT;
        float en0 = en_g[c0 + tm];
        float en1 = en_g[c0 + 16 + tm];
        __syncthreads();                   // staged tile visible
        tb += BNT * 512;

        v4f acc[2][2];
#pragma unroll
        for (int mi = 0; mi < 2; ++mi)
#pragma unroll
            for (int ni = 0; ni < 2; ++ni) acc[mi][ni] = (v4f)0.f;

#pragma unroll
        for (int kc = 0; kc < 8; ++kc) {
            int kx = (kc ^ hb) << 5;
            v8h bh0 = *(const v8h*)&esh[eb0 + kx];
            v8h bl0 = *(const v8h*)&esl[eb0 + kx];
            v8h bh1 = *(const v8h*)&esh[eb1 + kx];
            v8h bl1 = *(const v8h*)&esl[eb1 + kx];
#pragma unroll
            for (int mi = 0; mi < 2; ++mi) {
                acc[mi][0] = __builtin_amdgcn_mfma_f32_16x16x32_f16(zfh[mi][kc], bh0, acc[mi][0], 0, 0, 0);
                acc[mi][0] = __builtin_amdgcn_mfma_f32_16x16x32_f16(zfh[mi][kc], bl0, acc[mi][0], 0, 0, 0);
                acc[mi][0] = __builtin_amdgcn_mfma_f32_16x16x32_f16(zfl[mi][kc], bh0, acc[mi][0], 0, 0, 0);
                acc[mi][1] = __builtin_amdgcn_mfma_f32_16x16x32_f16(zfh[mi][kc], bh1, acc[mi][1], 0, 0, 0);
                acc[mi][1] = __builtin_amdgcn_mfma_f32_16x16x32_f16(zfh[mi][kc], bl1, acc[mi][1], 0, 0, 0);
                acc[mi][1] = __builtin_amdgcn_mfma_f32_16x16x32_f16(zfl[mi][kc], bh1, acc[mi][1], 0, 0, 0);
            }
        }

        // per-tile argmin update: score = ||e||^2 - 2*dot (codes ascending)
#pragma unroll
        for (int ni = 0; ni < 2; ++ni) {
            float en = ni ? en1 : en0;
            int code = c0 + ni * 16 + tm;
#pragma unroll
            for (int mi = 0; mi < 2; ++mi)
#pragma unroll
                for (int r = 0; r < 4; ++r) {
                    float s = fmaf(-2.f, acc[mi][ni][r], en);
                    int slot = mi * 4 + r;
                    if (s < rmin[slot]) { rmin[slot] = s; ridx[slot] = code; }
                }
        }
    }

    // ---- reduce across the 16 column-lanes (tm) per row; write partials ----
#pragma unroll
    for (int slot = 0; slot < 8; ++slot) {
        float bv = rmin[slot];
        int   bi = ridx[slot];
#pragma unroll
        for (int m = 1; m <= 8; m <<= 1) {
            float v2 = __shfl_xor(bv, m, 64);
            int   i2 = __shfl_xor(bi, m, 64);
            if (v2 < bv || (v2 == bv && i2 < bi)) { bv = v2; bi = i2; }
        }
        if (tm == 0) {
            int row = r0 + w * 32 + (slot >> 2) * 16 + q * 4 + (slot & 3);
            ((float*)(ws + WS_PV))[sp * MROWS + row] = bv;
            ((int*)(ws + WS_PI))[sp * MROWS + row] = bi;
        }
    }
}

// ---------------------------------------------------------------------------
// Kernel 3: merge 4 split-partials + gather + STE output + 1.25*MSE loss.
__global__ void quant_loss_kernel(const float* __restrict__ z,
                                  const float* __restrict__ emb,
                                  const char* __restrict__ ws,
                                  float* __restrict__ out) {
    __shared__ float wsum[4];
    const float* pv = (const float*)(ws + WS_PV);
    const int*   pi = (const int*)(ws + WS_PI);
    int tid = threadIdx.x, lane = tid & 63;
    int p = lane & 3;
    float lsum = 0.f;
#pragma unroll 1
    for (int it = 0; it < 16; ++it) {
        int f = it * 65536 + blockIdx.x * 256 + tid;   // float4 index
        int row = f >> 6, c4 = f & 63;
        float bv = pv[p * MROWS + row];
        int   bi = pi[p * MROWS + row];
#pragma unroll
        for (int m = 1; m <= 2; m <<= 1) {
            float v2 = __shfl_xor(bv, m, 64);
            int   i2 = __shfl_xor(bi, m, 64);
            if (v2 < bv || (v2 == bv && i2 < bi)) { bv = v2; bi = i2; }
        }
        if (c4 == 0) out[IDXOFF + row] = (float)bi;
        float4 qv = ((const float4*)(emb + (size_t)bi * CDIM))[c4];
        float4 zv = ((const float4*)z)[f];
        float dx = qv.x - zv.x, dy = qv.y - zv.y;
        float dz = qv.z - zv.z, dw = qv.w - zv.w;
        float4 o;   // match reference STE rounding: z + (q - z)
        o.x = zv.x + dx; o.y = zv.y + dy; o.z = zv.z + dz; o.w = zv.w + dw;
        ((float4*)out)[f] = o;
        lsum += dx * dx + dy * dy + dz * dz + dw * dw;
    }
#pragma unroll
    for (int m = 32; m >= 1; m >>= 1) lsum += __shfl_xor(lsum, m, 64);
    int wv = tid >> 6;
    if (lane == 0) wsum[wv] = lsum;
    __syncthreads();
    if (tid == 0) {
        float t = wsum[0] + wsum[1] + wsum[2] + wsum[3];
        atomicAdd(out + LOSS_OFF, t * (1.25f / 4194304.f));
    }
}

// ---------------------------------------------------------------------------
extern "C" void kernel_launch(void* const* d_in, const int* in_sizes, int n_in,
                              void* d_out, int out_size, void* d_ws, size_t ws_size,
                              hipStream_t stream) {
    const float* z   = (const float*)d_in[0];
    const float* emb = (const float*)d_in[1];
    float* out = (float*)d_out;
    char*  ws  = (char*)d_ws;   // ~25.7 MB used

    hipLaunchKernelGGL(split_enorm_kernel, dim3((MROWS + KCODES) / 4), dim3(256),
                       0, stream, z, emb, ws, out + LOSS_OFF);
    hipLaunchKernelGGL(vq_argmin_kernel, dim3((MROWS / BM) * NSPLIT), dim3(256),
                       0, stream, ws, ws);
    hipLaunchKernelGGL(quant_loss_kernel, dim3(256), dim3(256),
                       0, stream, z, emb, ws, out);
}